// Round 1
// baseline (795.978 us; speedup 1.0000x reference)
//
#include <hip/hip_runtime.h>
#include <math.h>

// SLAYFeatures: x[B, H*D] fp32, omega[R,H,D,M] fp32, quad_nodes[R], quad_weights[R]
// out[B, H*R*M] fp32.
// B=65536, H=16, D=64, M=32, R=2.
//
// Mapping: one wave handles one head h and a run of b's.
//   lane = r*32 + m  (R*M = 64 = wavefront)
//   omega[r,h,:,m] kept in 64 VGPRs per lane (loaded once).
//   x row slice (64 floats) is wave-uniform -> scalar loads (SGPRs),
//   dot = 64x v_fmac_f32 with SGPR src.
//   norm factored out: proj = (x . w) * rnorm.

#define HH 16
#define DD 64
#define MM 32
#define RR 2
#define BPW 64   // b's per wave
#define WPB 4    // waves per block (256 threads)

__global__ __launch_bounds__(256)
void slay_features_kernel(const float* __restrict__ x,
                          const float* __restrict__ omega,
                          const float* __restrict__ qn,
                          const float* __restrict__ qw,
                          float* __restrict__ out)
{
    const int tid  = threadIdx.x;
    const int lane = tid & 63;
    const int wave = tid >> 6;

    // h inner, b-chunk outer: adjacent blocks share the same x rows (L2/L3 reuse)
    const int h     = blockIdx.x & (HH - 1);
    const int chunk = blockIdx.x >> 4;

    const int r = lane >> 5;   // 0..1
    const int m = lane & 31;   // 0..31

    // per-lane quadrature constants
    const float s_node = qn[r];
    const float sqrt2s = sqrtf(2.0f * fmaxf(s_node, 0.0f));
    const float sqw    = sqrtf(fmaxf(qw[r], 0.0f));
    const float cr     = sqw * (1.0f / 32.0f);   // ism^2 * sqrt(w)

    // omega column for this lane: w[d] = omega[r, h, d, m]
    float w[DD];
    const float* wp = omega + ((size_t)(r * HH + h) * DD) * MM + m;
    #pragma unroll
    for (int d = 0; d < DD; ++d) w[d] = wp[(size_t)d * MM];

    const int b0 = chunk * (WPB * BPW) + wave * BPW;
    const float* xbase = x + (size_t)b0 * (HH * DD) + h * DD;

    for (int i = 0; i < BPW; ++i) {
        const float* __restrict__ xrow = xbase + (size_t)i * (HH * DD);

        // ---- norm: coalesced vector load + wave reduction ----
        float xv = xrow[lane];
        float ss = xv * xv;
        #pragma unroll
        for (int mask = 32; mask >= 1; mask >>= 1)
            ss += __shfl_xor(ss, mask, 64);
        const float rnorm = 1.0f / fmaxf(sqrtf(ss), 1e-6f);

        // ---- dot: uniform (scalar) x loads against per-lane omega column ----
        float acc = 0.0f;
        #pragma unroll
        for (int d = 0; d < DD; ++d)
            acc = fmaf(xrow[d], w[d], acc);

        // ---- epilogue ----
        const float proj = acc * rnorm;
        float ea = fmaf(proj, sqrt2s, -s_node);
        ea = fminf(fmaxf(ea, -10.0f), 10.0f);
        const float prf = __expf(ea);
        const float res = proj * proj * prf * cr;

        out[(size_t)(b0 + i) * (HH * RR * MM) + h * (RR * MM) + lane] = res;
    }
}

extern "C" void kernel_launch(void* const* d_in, const int* in_sizes, int n_in,
                              void* d_out, int out_size, void* d_ws, size_t ws_size,
                              hipStream_t stream) {
    const float* x     = (const float*)d_in[0];
    const float* omega = (const float*)d_in[1];
    const float* qn    = (const float*)d_in[2];
    const float* qw    = (const float*)d_in[3];
    float* out = (float*)d_out;

    const int B = in_sizes[0] / (HH * DD);          // 65536
    const int nchunks = B / (WPB * BPW);            // 256
    dim3 grid(nchunks * HH);                        // 4096 blocks, h = bid & 15
    dim3 block(WPB * 64);                           // 256 threads

    slay_features_kernel<<<grid, block, 0, stream>>>(x, omega, qn, qw, out);
}

// Round 2
// 242.989 us; speedup vs baseline: 3.2758x; 3.2758x over previous
//
#include <hip/hip_runtime.h>
#include <math.h>

// SLAYFeatures: x[B, H*D] fp32, omega[R,H,D,M] fp32, quad_nodes[R], quad_weights[R]
// out[B, H*R*M] fp32.  B=65536, H=16, D=64, M=32, R=2.
//
// Wave layout: lane = r*32+m (R*M == 64). Each wave owns one head h and 64
// consecutive b rows.
//   - omega column w[d] = omega[r,h,d,m] held in 64 VGPRs (loaded once).
//   - x row (64 floats) is wave-uniform: readfirstlane'd byte offset makes the
//     pointer provably uniform -> s_load_dwordx16 (SMEM), so the dot is
//     64x v_fmac_f32 with an SGPR multiplicand.
//   - norm factored out of the dot: proj = (x.w) * rsqrt(sum x^2); sum x^2 via
//     coalesced vector load (also warms L2 for the scalar re-read) + shfl tree.

#define HH 16
#define DD 64
#define MM 32
#define RR 2
#define BPW 64   // b rows per wave
#define WPB 4    // waves per block

__global__ __launch_bounds__(256, 4)
void slay_features_kernel(const float* __restrict__ x,
                          const float* __restrict__ omega,
                          const float* __restrict__ qn,
                          const float* __restrict__ qw,
                          float* __restrict__ out)
{
    const int tid  = threadIdx.x;
    const int lane = tid & 63;
    const int wave = tid >> 6;

    const int h     = blockIdx.x & (HH - 1);
    const int chunk = blockIdx.x >> 4;

    const int r = lane >> 5;   // 0..1
    const int m = lane & 31;   // 0..31

    // per-lane quadrature constants
    const float s_node = qn[r];
    const float sqrt2s = sqrtf(2.0f * fmaxf(s_node, 0.0f));
    const float sqw    = sqrtf(fmaxf(qw[r], 0.0f));
    const float cr     = sqw * (1.0f / (float)MM);   // inv_sqrt_m^2 * sqrt(w)

    // omega column for this lane: w[d] = omega[r, h, d, m]  (64 VGPRs, loaded once)
    float w[DD];
    const float* wp = omega + ((size_t)(r * HH + h) * DD) * MM + m;
    #pragma unroll
    for (int d = 0; d < DD; ++d) w[d] = wp[(size_t)d * MM];

    const int b0 = chunk * (WPB * BPW) + wave * BPW;

    // wave-uniform byte offset of this wave's x row slice (fits 32 bits: <=2^28)
    unsigned int base_off = (unsigned int)b0 * (HH * DD * 4u)
                          + (unsigned int)h  * (DD * 4u);
    base_off = __builtin_amdgcn_readfirstlane(base_off);

    float* orow = out + (size_t)b0 * (HH * RR * MM) + (size_t)h * (RR * MM) + lane;

    for (int i = 0; i < BPW; ++i) {
        const unsigned int off =
            __builtin_amdgcn_readfirstlane(base_off + (unsigned int)i * (HH * DD * 4u));
        const float* __restrict__ xrow = (const float*)((const char*)x + off);

        // ---- norm: coalesced vector load + wave shfl reduction ----
        const float xv = xrow[lane];
        float ss = xv * xv;
        #pragma unroll
        for (int mask = 32; mask >= 1; mask >>= 1)
            ss += __shfl_xor(ss, mask, 64);
        const float rnorm = 1.0f / fmaxf(sqrtf(ss), 1e-6f);

        // ---- dot: uniform (SGPR) x values against per-lane omega column ----
        float acc = 0.0f;
        #pragma unroll
        for (int d = 0; d < DD; ++d)
            acc = fmaf(xrow[d], w[d], acc);

        // ---- epilogue ----
        const float proj = acc * rnorm;
        float ea = fmaf(proj, sqrt2s, -s_node);
        ea = fminf(fmaxf(ea, -10.0f), 10.0f);
        const float prf = __expf(ea);
        const float res = proj * proj * prf * cr;

        __builtin_nontemporal_store(res, orow);
        orow += HH * RR * MM;
    }
}

extern "C" void kernel_launch(void* const* d_in, const int* in_sizes, int n_in,
                              void* d_out, int out_size, void* d_ws, size_t ws_size,
                              hipStream_t stream) {
    const float* x     = (const float*)d_in[0];
    const float* omega = (const float*)d_in[1];
    const float* qn    = (const float*)d_in[2];
    const float* qw    = (const float*)d_in[3];
    float* out = (float*)d_out;

    const int B = in_sizes[0] / (HH * DD);          // 65536
    const int nchunks = B / (WPB * BPW);            // 256
    dim3 grid(nchunks * HH);                        // 4096 blocks, h = bid & 15
    dim3 block(WPB * 64);                           // 256 threads

    slay_features_kernel<<<grid, block, 0, stream>>>(x, omega, qn, qw, out);
}

// Round 3
// 230.950 us; speedup vs baseline: 3.4465x; 1.0521x over previous
//
#include <hip/hip_runtime.h>
#include <math.h>

// SLAYFeatures: x[B, H*D] fp32, omega[R,H,D,M] fp32, quad_nodes[R], quad_weights[R]
// out[B, H*R*M] fp32.  B=65536, H=16, D=64, M=32, R=2.
//
// Wave layout: lane = r*32+m (R*M == 64). Each wave owns one head h and 64
// consecutive b rows.
//   - omega column w[d] = omega[r,h,d,m] held in 64 VGPRs, PINNED with an
//     asm keep-alive so the compiler can't sink the loads into the b-loop
//     (round-2 failure mode: VGPR_Count=44 -> 64 VMEM reloads per row).
//   - x row (64 floats) is wave-uniform via readfirstlane'd offset ->
//     s_load_dwordx16; dot = 64x v_fmac_f32 with SGPR multiplicand.
//   - norm factored out: proj = (x.w) * rsqrt(sum x^2); sum via coalesced
//     vector load + 6-step shfl_xor tree.

#define HH 16
#define DD 64
#define MM 32
#define RR 2
#define BPW 64   // b rows per wave
#define WPB 4    // waves per block

__global__ __launch_bounds__(256, 4)
void slay_features_kernel(const float* __restrict__ x,
                          const float* __restrict__ omega,
                          const float* __restrict__ qn,
                          const float* __restrict__ qw,
                          float* __restrict__ out)
{
    const int tid  = threadIdx.x;
    const int lane = tid & 63;
    const int wave = tid >> 6;

    const int h     = blockIdx.x & (HH - 1);
    const int chunk = blockIdx.x >> 4;

    const int r = lane >> 5;   // 0..1
    const int m = lane & 31;   // 0..31

    // per-lane quadrature constants
    const float s_node = qn[r];
    const float sqrt2s = sqrtf(2.0f * fmaxf(s_node, 0.0f));
    const float sqw    = sqrtf(fmaxf(qw[r], 0.0f));
    const float cr     = sqw * (1.0f / (float)MM);   // inv_sqrt_m^2 * sqrt(w)

    // omega column for this lane: w[d] = omega[r, h, d, m]  (64 VGPRs)
    float w[DD];
    const float* wp = omega + ((size_t)(r * HH + h) * DD) * MM + m;
    #pragma unroll
    for (int d = 0; d < DD; ++d) w[d] = wp[(size_t)d * MM];

    // Pin: opaque redefinition prevents the loads from being sunk into the
    // b-loop (they must complete here) and forces VGPR residency.
    #pragma unroll
    for (int d = 0; d < DD; ++d) asm volatile("" : "+v"(w[d]));

    const int b0 = chunk * (WPB * BPW) + wave * BPW;

    // wave-uniform byte offset of this wave's x row slice (fits 32 bits)
    unsigned int base_off = (unsigned int)b0 * (HH * DD * 4u)
                          + (unsigned int)h  * (DD * 4u);
    base_off = __builtin_amdgcn_readfirstlane(base_off);

    float* orow = out + (size_t)b0 * (HH * RR * MM) + (size_t)h * (RR * MM) + lane;

    for (int i = 0; i < BPW; ++i) {
        const unsigned int off =
            __builtin_amdgcn_readfirstlane(base_off + (unsigned int)i * (HH * DD * 4u));
        const float* __restrict__ xrow = (const float*)((const char*)x + off);

        // ---- norm: coalesced vector load + wave shfl reduction ----
        const float xv = xrow[lane];
        float ss = xv * xv;
        #pragma unroll
        for (int mask = 32; mask >= 1; mask >>= 1)
            ss += __shfl_xor(ss, mask, 64);
        const float rnorm = 1.0f / fmaxf(sqrtf(ss), 1e-6f);

        // ---- dot: uniform (SGPR) x values against pinned omega column ----
        float acc = 0.0f;
        #pragma unroll
        for (int d = 0; d < DD; ++d)
            acc = fmaf(xrow[d], w[d], acc);

        // ---- epilogue ----
        const float proj = acc * rnorm;
        float ea = fmaf(proj, sqrt2s, -s_node);
        ea = fminf(fmaxf(ea, -10.0f), 10.0f);
        const float prf = __expf(ea);
        const float res = proj * proj * prf * cr;

        __builtin_nontemporal_store(res, orow);
        orow += HH * RR * MM;
    }
}

extern "C" void kernel_launch(void* const* d_in, const int* in_sizes, int n_in,
                              void* d_out, int out_size, void* d_ws, size_t ws_size,
                              hipStream_t stream) {
    const float* x     = (const float*)d_in[0];
    const float* omega = (const float*)d_in[1];
    const float* qn    = (const float*)d_in[2];
    const float* qw    = (const float*)d_in[3];
    float* out = (float*)d_out;

    const int B = in_sizes[0] / (HH * DD);          // 65536
    const int nchunks = B / (WPB * BPW);            // 256
    dim3 grid(nchunks * HH);                        // 4096 blocks, h = bid & 15
    dim3 block(WPB * 64);                           // 256 threads

    slay_features_kernel<<<grid, block, 0, stream>>>(x, omega, qn, qw, out);
}